// Round 1
// baseline (135.997 us; speedup 1.0000x reference)
//
#include <hip/hip_runtime.h>

// out[m][e*5+c] = x[m,c]*w_c[e] + (b_c[e] + ot[c][e]);  M=65536, E=512
// Memory-bound: 640 MiB f32 write. Strategy:
//   - thread t of a 128-thread row-group owns floats 20t..20t+19 of the row
//     (e = 4t..4t+3, c = 0..4) -> all table indices compile-time constant
//   - per-thread table slices (w, b+ot) hoisted to registers (loop-invariant)
//   - stage each 2-row tile in LDS, then perfectly coalesced float4 stores

#define ROWS_PER_IT 2
#define ITERS 16

__global__ __launch_bounds__(256) void pc_kernel(
    const float* __restrict__ x,
    const float* __restrict__ w_bet,  const float* __restrict__ b_bet,
    const float* __restrict__ w_stk,  const float* __restrict__ b_stk,
    const float* __restrict__ w_call, const float* __restrict__ b_call,
    const float* __restrict__ w_odds, const float* __restrict__ b_odds,
    const float* __restrict__ ot,
    float* __restrict__ out)
{
    __shared__ float4 stage[1280];           // 2 rows x 2560 floats = 20 KB
    const int tid  = threadIdx.x;
    const int t0   = tid & 127;              // thread-in-row (e base = 4*t0)
    const int half = tid >> 7;               // which row of the pair

    // ---- hoist per-thread table slices into registers (loop-invariant) ----
    const float* wsrc[5] = {w_bet, w_stk, w_stk, w_call, w_odds};
    const float* bsrc[5] = {b_bet, b_stk, b_stk, b_call, b_odds};
    float wv[5][4], bv[5][4];
#pragma unroll
    for (int c = 0; c < 5; ++c) {
        float4 w4 = reinterpret_cast<const float4*>(wsrc[c])[t0];
        float4 b4 = reinterpret_cast<const float4*>(bsrc[c])[t0];
        float4 o4 = reinterpret_cast<const float4*>(ot + 512 * c)[t0];
        wv[c][0] = w4.x; wv[c][1] = w4.y; wv[c][2] = w4.z; wv[c][3] = w4.w;
        bv[c][0] = b4.x + o4.x; bv[c][1] = b4.y + o4.y;
        bv[c][2] = b4.z + o4.z; bv[c][3] = b4.w + o4.w;
    }

    const long long rp_base = (long long)blockIdx.x * ITERS;

    for (int it = 0; it < ITERS; ++it) {
        const long long rp = rp_base + it;               // row-pair index
        const int m = (int)(2 * rp) + half;

        // x row (wave-uniform address -> broadcast loads, L1/L2 hit)
        const float* xr = x + m * 5;
        float xs[5];
#pragma unroll
        for (int c = 0; c < 5; ++c) xs[c] = xr[c];

        // 20 output values: v[j][c] = out[m][(4*t0+j)*5 + c]
        float v[4][5];
#pragma unroll
        for (int j = 0; j < 4; ++j)
#pragma unroll
            for (int c = 0; c < 5; ++c)
                v[j][c] = fmaf(xs[c], wv[c][j], bv[c][j]);

        // pack into 5 float4s and stage in LDS (word-stride 20 => bank-uniform)
        float4* st = stage + half * 640 + t0 * 5;
#pragma unroll
        for (int q = 0; q < 5; ++q) {
            float4 f;
            f.x = v[(4 * q + 0) / 5][(4 * q + 0) % 5];
            f.y = v[(4 * q + 1) / 5][(4 * q + 1) % 5];
            f.z = v[(4 * q + 2) / 5][(4 * q + 2) % 5];
            f.w = v[(4 * q + 3) / 5][(4 * q + 3) % 5];
            st[q] = f;
        }
        __syncthreads();

        // coalesced copy: 1280 float4s (20 KB contiguous) per iteration
        float4* dst = reinterpret_cast<float4*>(out) + rp * 1280;
#pragma unroll
        for (int k = 0; k < 5; ++k)
            dst[tid + 256 * k] = stage[tid + 256 * k];
        __syncthreads();
    }
}

extern "C" void kernel_launch(void* const* d_in, const int* in_sizes, int n_in,
                              void* d_out, int out_size, void* d_ws, size_t ws_size,
                              hipStream_t stream) {
    const float* x      = (const float*)d_in[0];
    const float* w_bet  = (const float*)d_in[1];
    const float* b_bet  = (const float*)d_in[2];
    const float* w_stk  = (const float*)d_in[3];
    const float* b_stk  = (const float*)d_in[4];
    const float* w_call = (const float*)d_in[5];
    const float* b_call = (const float*)d_in[6];
    const float* w_odds = (const float*)d_in[7];
    const float* b_odds = (const float*)d_in[8];
    const float* ot     = (const float*)d_in[9];
    float* out = (float*)d_out;

    const int M = in_sizes[0] / 5;                   // 65536
    const int grid = M / (ROWS_PER_IT * ITERS);      // 2048 blocks

    pc_kernel<<<grid, 256, 0, stream>>>(x, w_bet, b_bet, w_stk, b_stk,
                                        w_call, b_call, w_odds, b_odds, ot, out);
}